// Round 6
// baseline (203.634 us; speedup 1.0000x reference)
//
#include <hip/hip_runtime.h>

#define BB 2
#define NN 768
#define FF 128
#define HH 128
#define DELTA 0.05f
#define WCAP (1u << 20)
#define T16 48
#define TUP (T16 * (T16 + 1) / 2)   // 1176 upper 16x16 tiles
#define TOTW (TUP * BB)             // 2352 wave-tiles

typedef __attribute__((ext_vector_type(8))) short bf16x8;
typedef __attribute__((ext_vector_type(4))) float f32x4;

__device__ __forceinline__ unsigned short f2b(float x) {
    union { float f; unsigned u; } v; v.f = x; return (unsigned short)(v.u >> 16);
}
__device__ __forceinline__ float b2f(unsigned short h) {
    union { float f; unsigned u; } v; v.u = ((unsigned)h) << 16; return v.f;
}

// k1: edge-feat MLP in f64 (authority). Outputs Xc64 (f64) and bf16 hi/lo split
// planes for the MFMA fast path. Block 0 packs: wpack64 (f64 repair weights),
// wq (ready A-frag 8xushort per hidden: [ahi,bhi,ahi,bhi,alo,blo,Bhi,Blo]),
// wdf (f32 wd), zeroes counter.
__global__ __launch_bounds__(256)
void edgefeat_kernel(const float* __restrict__ X,
                     const float* __restrict__ w1, const float* __restrict__ b1,
                     const float* __restrict__ w2, const float* __restrict__ b2,
                     const float* __restrict__ gatep,
                     const float* __restrict__ sm_w1, const float* __restrict__ sm_b1,
                     const float* __restrict__ sm_w2,
                     double* __restrict__ Xc64,
                     unsigned short* __restrict__ Xhi, unsigned short* __restrict__ Xlo,
                     double* __restrict__ wpack64,
                     unsigned short* __restrict__ wq, float* __restrict__ wdf,
                     unsigned* __restrict__ counter) {
    __shared__ float  Xs[2][FF];
    __shared__ double Hs[2][HH + 2];
    const int tid = threadIdx.x;
    const int r = tid >> 7;        // 0..1
    const int c = tid & 127;       // 0..127
    const int row0 = blockIdx.x * 2;

    if (blockIdx.x == 0 && r == 0) {
        double a  = (double)sm_w1[c];
        double bb = (double)sm_w1[HH + c];
        double be = (double)sm_b1[c];
        double wd = (double)sm_w2[2 * c + 1] - (double)sm_w2[2 * c];
        wpack64[4 * c + 0] = a;  wpack64[4 * c + 1] = bb;
        wpack64[4 * c + 2] = be; wpack64[4 * c + 3] = wd;
        float af = (float)a, bf = (float)bb, ef = (float)be;
        unsigned short ah = f2b(af), bh = f2b(bf), eh = f2b(ef);
        unsigned short al = f2b(af - b2f(ah)), bl = f2b(bf - b2f(bh)), el = f2b(ef - b2f(eh));
        wq[8 * c + 0] = ah; wq[8 * c + 1] = bh;
        wq[8 * c + 2] = ah; wq[8 * c + 3] = bh;
        wq[8 * c + 4] = al; wq[8 * c + 5] = bl;
        wq[8 * c + 6] = eh; wq[8 * c + 7] = el;
        wdf[c] = (float)wd;
        if (c == 0) *counter = 0u;
    }

    Xs[r][c] = X[(size_t)(row0 + r) * FF + c];
    __syncthreads();

    double acc0 = (double)b1[c], acc1 = 0.0;
#pragma unroll 8
    for (int f = 0; f < 64; ++f) {
        acc0 = fma((double)Xs[r][f],      (double)w1[f * HH + c],        acc0);
        acc1 = fma((double)Xs[r][f + 64], (double)w1[(f + 64) * HH + c], acc1);
    }
    double h1 = acc0 + acc1;
    Hs[r][c] = h1 > 0.0 ? h1 : 0.0;
    __syncthreads();

    acc0 = (double)b2[c]; acc1 = 0.0;
#pragma unroll 8
    for (int f = 0; f < 64; ++f) {
        acc0 = fma(Hs[r][f],      (double)w2[f * HH + c],        acc0);
        acc1 = fma(Hs[r][f + 64], (double)w2[(f + 64) * HH + c], acc1);
    }

    const double gate = (double)gatep[0];
    double v = (double)Xs[r][c] + gate * (acc0 + acc1);
    const int g = row0 + r;
    const int b = g / NN, i = g % NN;
    const int k = c & 1, d = c >> 1;
    size_t idx = (((size_t)(b * 2 + k)) * NN + i) * 64 + d;
    Xc64[idx] = v;
    float x32 = (float)v;
    unsigned short hi = f2b(x32);
    Xhi[idx] = hi;
    Xlo[idx] = f2b(x32 - b2f(hi));
}

// k2: MFMA fast pass. One 16x16 edge tile per wave.
// Gram via split-bf16 MFMA (16/tile), MLP z via MFMA (M=hidden, N=edges,
// K-packed splits+bias), relu+wd epilogue in VALU, 2-shuffle reduce.
__global__ __launch_bounds__(256)
void decide_kernel(const unsigned short* __restrict__ Xhi,
                   const unsigned short* __restrict__ Xlo,
                   const unsigned short* __restrict__ wq,
                   const float* __restrict__ wdf,
                   const float* __restrict__ sm_b2,
                   const float* __restrict__ gumbel,
                   float* __restrict__ out,
                   unsigned* __restrict__ counter,
                   unsigned* __restrict__ worklist) {
    __shared__ float scr[4][512];    // wave-private P scratch (16x16 x {p0,p1})
    const int tid = threadIdx.x;
    const int wv = tid >> 6, lane = tid & 63;
    const int lq = lane >> 4, ln = lane & 15;
    int t = blockIdx.x * 4 + wv;
    if (t >= TOTW) return;
    const int b = (t >= TUP) ? 1 : 0;
    int tt = t - b * TUP;
    int ti = 0;
    while (tt >= T16 - ti) { tt -= T16 - ti; ++ti; }
    const int tj = ti + tt;
    const int i0 = ti * 16, j0 = tj * 16;
    const bool diag = (ti == tj);

    const bf16x8 zv8 = {0, 0, 0, 0, 0, 0, 0, 0};
    const f32x4  zv4 = {0.f, 0.f, 0.f, 0.f};

    // per-wave static weight frags (A-operand, M=hidden): lanes 0..15 carry k=0..7
    bf16x8 Wf[8];
    float wdv[32];
#pragma unroll
    for (int g = 0; g < 8; ++g) {
        bf16x8 w = *(const bf16x8*)&wq[(g * 16 + ln) * 8];
        Wf[g] = (lq == 0) ? w : zv8;
#pragma unroll
        for (int rr = 0; rr < 4; ++rr)
            wdv[g * 4 + rr] = wdf[g * 16 + lq * 4 + rr];
    }

    // gumbel prefetch for all 16 groups (hide HBM latency under gram+MLP)
    float2 garr[16];
#pragma unroll
    for (int rr = 0; rr < 16; ++rr)
        garr[rr] = *(const float2*)&gumbel[(((size_t)b * NN + i0 + rr) * NN + j0 + ln) * 2];

    // gram: P[k][i][j] via split-bf16 MFMAs, frags straight from global hi/lo
    size_t bi0 = (((size_t)(b * 2 + 0)) * NN + i0 + ln) * 64 + lq * 8;
    size_t bi1 = (((size_t)(b * 2 + 1)) * NN + i0 + ln) * 64 + lq * 8;
    size_t bj0 = (((size_t)(b * 2 + 0)) * NN + j0 + ln) * 64 + lq * 8;
    size_t bj1 = (((size_t)(b * 2 + 1)) * NN + j0 + ln) * 64 + lq * 8;
    f32x4 P0 = zv4, P1 = zv4;
#pragma unroll
    for (int h = 0; h < 2; ++h) {
        bf16x8 aih = *(const bf16x8*)&Xhi[bi0 + h * 32];
        bf16x8 ail = *(const bf16x8*)&Xlo[bi0 + h * 32];
        bf16x8 bjh = *(const bf16x8*)&Xhi[bj0 + h * 32];
        bf16x8 bjl = *(const bf16x8*)&Xlo[bj0 + h * 32];
        P0 = __builtin_amdgcn_mfma_f32_16x16x32_bf16(aih, bjh, P0, 0, 0, 0);
        P0 = __builtin_amdgcn_mfma_f32_16x16x32_bf16(aih, bjl, P0, 0, 0, 0);
        P0 = __builtin_amdgcn_mfma_f32_16x16x32_bf16(ail, bjh, P0, 0, 0, 0);
        P0 = __builtin_amdgcn_mfma_f32_16x16x32_bf16(ail, bjl, P0, 0, 0, 0);
        bf16x8 cih = *(const bf16x8*)&Xhi[bi1 + h * 32];
        bf16x8 cil = *(const bf16x8*)&Xlo[bi1 + h * 32];
        bf16x8 djh = *(const bf16x8*)&Xhi[bj1 + h * 32];
        bf16x8 djl = *(const bf16x8*)&Xlo[bj1 + h * 32];
        P1 = __builtin_amdgcn_mfma_f32_16x16x32_bf16(cih, djh, P1, 0, 0, 0);
        P1 = __builtin_amdgcn_mfma_f32_16x16x32_bf16(cih, djl, P1, 0, 0, 0);
        P1 = __builtin_amdgcn_mfma_f32_16x16x32_bf16(cil, djh, P1, 0, 0, 0);
        P1 = __builtin_amdgcn_mfma_f32_16x16x32_bf16(cil, djl, P1, 0, 0, 0);
    }

    // P C-layout -> per-edge scratch (wave-private, no barrier)
    float* s = scr[wv];
#pragma unroll
    for (int rr = 0; rr < 4; ++rr)
        *(float2*)&s[((lq * 4 + rr) * 16 + ln) * 2] = make_float2(P0[rr], P1[rr]);

    const float bd = sm_b2[1] - sm_b2[0];
    const unsigned short ONE = 0x3F80;

#pragma unroll 2
    for (int r = 0; r < 16; ++r) {
        float2 p = *(const float2*)&s[(r * 16 + ln) * 2];
        unsigned short h0 = f2b(p.x), h1 = f2b(p.y);
        unsigned short l0 = f2b(p.x - b2f(h0)), l1 = f2b(p.y - b2f(h1));
        bf16x8 Bf = {(short)h0, (short)h1, (short)l0, (short)l1,
                     (short)h0, (short)h1, (short)ONE, (short)ONE};
        if (lq != 0) Bf = zv8;
        float acc = 0.f;
#pragma unroll
        for (int g = 0; g < 8; ++g) {
            f32x4 Z = __builtin_amdgcn_mfma_f32_16x16x32_bf16(Wf[g], Bf, zv4, 0, 0, 0);
#pragma unroll
            for (int rr = 0; rr < 4; ++rr)
                acc = fmaf(fmaxf(Z[rr], 0.f), wdv[g * 4 + rr], acc);
        }
        acc += __shfl_xor(acc, 16, 64);
        acc += __shfl_xor(acc, 32, 64);

        const int i = i0 + r, j = j0 + ln;
        float m = bd + (garr[r].y - garr[r].x) + acc;
        float val = m > 0.f ? 1.f : 0.f;
        if (lq == 0) {
            if (!diag) out[((size_t)b * NN + i) * NN + j] = val;
            else if (j >= i) out[((size_t)b * NN + i) * NN + j] = (j > i) ? val : 0.f;
        } else if (lq == 1) {
            if (!diag || j > i) out[((size_t)b * NN + j) * NN + i] = val;
        } else if (lq == 2) {
            if ((!diag || j > i) && fabsf(m) < DELTA) {
                unsigned slot = atomicAdd(counter, 1u);
                if (slot < WCAP)
                    worklist[slot] = ((unsigned)(b * NN + i)) * NN + (unsigned)j;
            }
        }
    }
}

// k3: exact f64 re-adjudication of flagged edges
__global__ __launch_bounds__(64)
void repair_kernel(const double* __restrict__ Xc64,
                   const double* __restrict__ wpack64,
                   const float* __restrict__ sm_b2,
                   const float* __restrict__ gumbel,
                   float* __restrict__ out,
                   const unsigned* __restrict__ counter,
                   const unsigned* __restrict__ worklist) {
    unsigned n = *counter;
    if (n > WCAP) n = WCAP;
    for (unsigned t = blockIdx.x * blockDim.x + threadIdx.x; t < n;
         t += gridDim.x * blockDim.x) {
        unsigned e = worklist[t];
        int j = e % NN;
        unsigned rr = e / NN;
        int i = rr % NN;
        int b = rr / NN;
        const double* xi0 = &Xc64[(((size_t)(b * 2 + 0)) * NN + i) * 64];
        const double* xj0 = &Xc64[(((size_t)(b * 2 + 0)) * NN + j) * 64];
        const double* xi1 = &Xc64[(((size_t)(b * 2 + 1)) * NN + i) * 64];
        const double* xj1 = &Xc64[(((size_t)(b * 2 + 1)) * NN + j) * 64];
        double p0a = 0, p0b = 0, p1a = 0, p1b = 0;
        for (int d = 0; d < 64; d += 2) {
            p0a = fma(xi0[d],     xj0[d],     p0a);
            p0b = fma(xi0[d + 1], xj0[d + 1], p0b);
            p1a = fma(xi1[d],     xj1[d],     p1a);
            p1b = fma(xi1[d + 1], xj1[d + 1], p1b);
        }
        double p0 = p0a + p0b, p1 = p1a + p1b;
        const float* g = &gumbel[(((size_t)b * NN + i) * NN + j) * 2];
        double mA = ((double)sm_b2[1] - (double)sm_b2[0]) + ((double)g[1] - (double)g[0]);
        double mB = 0.0;
        for (int c = 0; c < HH; c += 2) {
            double2 wab0 = *(const double2*)&wpack64[4 * c];
            double2 wbw0 = *(const double2*)&wpack64[4 * c + 2];
            double2 wab1 = *(const double2*)&wpack64[4 * c + 4];
            double2 wbw1 = *(const double2*)&wpack64[4 * c + 6];
            double t0 = fma(p1, wab0.y, fma(p0, wab0.x, wbw0.x));
            double t1 = fma(p1, wab1.y, fma(p0, wab1.x, wbw1.x));
            t0 = fmax(t0, 0.0); t1 = fmax(t1, 0.0);
            mA = fma(t0, wbw0.y, mA);
            mB = fma(t1, wbw1.y, mB);
        }
        float v = (mA + mB) > 0.0 ? 1.f : 0.f;
        out[((size_t)b * NN + i) * NN + j] = v;
        out[((size_t)b * NN + j) * NN + i] = v;
    }
}

extern "C" void kernel_launch(void* const* d_in, const int* in_sizes, int n_in,
                              void* d_out, int out_size, void* d_ws, size_t ws_size,
                              hipStream_t stream) {
    const float* X      = (const float*)d_in[0];
    const float* ef_w1  = (const float*)d_in[1];
    const float* ef_b1  = (const float*)d_in[2];
    const float* ef_w2  = (const float*)d_in[3];
    const float* ef_b2  = (const float*)d_in[4];
    const float* gate   = (const float*)d_in[5];
    const float* sm_w1  = (const float*)d_in[6];
    const float* sm_b1  = (const float*)d_in[7];
    const float* sm_w2  = (const float*)d_in[8];
    const float* sm_b2  = (const float*)d_in[9];
    const float* gumbel = (const float*)d_in[10];
    float* out = (float*)d_out;

    double*         Xc64     = (double*)d_ws;                         // 196608 f64
    unsigned short* Xhi      = (unsigned short*)(Xc64 + 196608);      // 196608 u16
    unsigned short* Xlo      = Xhi + 196608;                          // 196608 u16
    double*         wpack64  = (double*)(Xlo + 196608);               // 512 f64
    unsigned short* wq       = (unsigned short*)(wpack64 + 512);      // 1024 u16
    float*          wdf      = (float*)(wq + 1024);                   // 128 f32
    unsigned*       counter  = (unsigned*)(wdf + 128);
    unsigned*       worklist = counter + 4;                           // WCAP entries

    edgefeat_kernel<<<BB * NN / 2, 256, 0, stream>>>(
        X, ef_w1, ef_b1, ef_w2, ef_b2, gate, sm_w1, sm_b1, sm_w2,
        Xc64, Xhi, Xlo, wpack64, wq, wdf, counter);
    decide_kernel<<<(TOTW + 3) / 4, 256, 0, stream>>>(
        Xhi, Xlo, wq, wdf, sm_b2, gumbel, out, counter, worklist);
    repair_kernel<<<64, 64, 0, stream>>>(Xc64, wpack64, sm_b2, gumbel, out,
                                         counter, worklist);
}